// Round 9
// baseline (189.232 us; speedup 1.0000x reference)
//
#include <hip/hip_runtime.h>

// ---------------------------------------------------------------------------
// StateBank: g = W_out @ scan(W_in @ u), restructured as
//   M_k = W_out_k @ W_in_k  (composite, k=0..3, each 1024x1024)
//   Y[b,t,(k,d)] = sum_d' M_k[d,d'] u[b,t,d']       (one 8192x4096x1024 GEMM)
//   z_k / g via chunked parallel scan; s_last via weighted time-reduction.
// Big GEMM: 256x256, BK=64, 8 waves, free-running K-tile interior, 2
// barriers/K-tile, counted vmcnt(8). LDS layout is FRAGMENT-MAJOR:
//   (row,k) -> rg*1024B + kq*256B + rsel*16B  (rg=row>>4, rsel=row&15, kq=k>>3)
// so a wave's ds_read_b128 is base + lane*16 (lane-monotonic, conflict-free;
// R4-R8 had 4.0 conflict-cycles per read from the 64B-stride row-major map).
// Staging: linear global_load_lds dest + inverse-permuted global source.
// ---------------------------------------------------------------------------

#define Bb 4
#define Tt 2048
#define Dd 1024
#define Kk 4
#define BT (Bb*Tt)          // 8192
#define Ee (Kk*Dd)          // 4096
#define NCH 32              // scan chunks
#define LCH 64              // chunk length (NCH*LCH = T)

typedef __bf16 bf16x8 __attribute__((ext_vector_type(8)));
typedef float  f32x4  __attribute__((ext_vector_type(4)));

__device__ __forceinline__ float bf2f(ushort u){
  union { unsigned int i; float f; } x; x.i = ((unsigned int)u) << 16; return x.f;
}
__device__ __forceinline__ ushort f2bf(float f){
  union { unsigned int i; float f; } x; x.f = f;
  unsigned int i = x.i;
  return (ushort)((i + 0x7FFFu + ((i >> 16) & 1u)) >> 16);   // RNE
}
__device__ __forceinline__ float sigm(float x){ return 1.0f / (1.0f + expf(-x)); }

// ---------------- convert f32 -> bf16 (vectorized) ----------------
__global__ __launch_bounds__(256) void k_f2bf4(const float4* __restrict__ in,
                                               ushort4* __restrict__ out, int n4){
  int i = blockIdx.x * 256 + threadIdx.x;
  if (i < n4){
    float4 v = in[i];
    ushort4 o; o.x = f2bf(v.x); o.y = f2bf(v.y); o.z = f2bf(v.z); o.w = f2bf(v.w);
    out[i] = o;
  }
}

// ---------------- transpose W_in (4096x1024 f32) -> WinT (1024x4096 bf16) ---
__global__ __launch_bounds__(256) void k_transpose(const float* __restrict__ in,
                                                   ushort* __restrict__ out){
  __shared__ float tile[32][33];
  int tx = threadIdx.x, ty = threadIdx.y;          // 32 x 8
  int c0 = blockIdx.x * 32, r0 = blockIdx.y * 32;  // cols of in, rows of in
  #pragma unroll
  for (int j = 0; j < 4; ++j)
    tile[ty + j*8][tx] = in[(size_t)(r0 + ty + j*8) * Dd + c0 + tx];
  __syncthreads();
  #pragma unroll
  for (int j = 0; j < 4; ++j)
    out[(size_t)(c0 + ty + j*8) * Ee + r0 + tx] = f2bf(tile[tx][ty + j*8]);
}

// ---------------- small NT GEMM (m97 structure) for Mcat --------------------
__global__ __launch_bounds__(256) void gemm_nt(const ushort* __restrict__ A,
                                               const ushort* __restrict__ B,
                                               ushort* __restrict__ C,
                                               int Kred, int lda, int ldb, int ldc,
                                               long aBatch, long bBatch, long cBatch){
  __shared__ ushort As[128 * 32];
  __shared__ ushort Bs[128 * 32];
  A += (long)blockIdx.z * aBatch;
  B += (long)blockIdx.z * bBatch;
  C += (long)blockIdx.z * cBatch;
  const int tid  = threadIdx.x;
  const int lane = tid & 63;
  const int w    = tid >> 6;
  const int wr   = w >> 1, wc = w & 1;
  const int rowBase = blockIdx.x * 128;
  const int colBase = blockIdx.y * 128;

  f32x4 acc[4][4] = {};
  const int krow = (lane >> 4) * 8;
  const int rsel = lane & 15;

  for (int kk = 0; kk < Kred; kk += 32){
    __syncthreads();
    #pragma unroll
    for (int i = 0; i < 2; ++i){
      int c  = i * 256 + tid;
      int r  = c >> 2;
      int c8 = (c & 3) * 8;
      const ushort* ga = A + (size_t)(rowBase + r) * lda + kk + c8;
      const ushort* gb = B + (size_t)(colBase + r) * ldb + kk + c8;
      __builtin_amdgcn_global_load_lds((const __attribute__((address_space(1))) void*)ga,
                                       (__attribute__((address_space(3))) void*)&As[c * 8],
                                       16, 0, 0);
      __builtin_amdgcn_global_load_lds((const __attribute__((address_space(1))) void*)gb,
                                       (__attribute__((address_space(3))) void*)&Bs[c * 8],
                                       16, 0, 0);
    }
    asm volatile("s_waitcnt vmcnt(0)" ::: "memory");
    __syncthreads();

    bf16x8 Af[4], Bf[4];
    #pragma unroll
    for (int mi = 0; mi < 4; ++mi)
      Af[mi] = *(const bf16x8*)&As[(wr*64 + mi*16 + rsel) * 32 + krow];
    #pragma unroll
    for (int ni = 0; ni < 4; ++ni)
      Bf[ni] = *(const bf16x8*)&Bs[(wc*64 + ni*16 + rsel) * 32 + krow];
    #pragma unroll
    for (int mi = 0; mi < 4; ++mi)
      #pragma unroll
      for (int ni = 0; ni < 4; ++ni)
        acc[mi][ni] = __builtin_amdgcn_mfma_f32_16x16x32_bf16(Af[mi], Bf[ni], acc[mi][ni], 0, 0, 0);
  }

  #pragma unroll
  for (int mi = 0; mi < 4; ++mi){
    #pragma unroll
    for (int ni = 0; ni < 4; ++ni){
      int r0 = rowBase + wr*64 + mi*16 + (lane >> 4) * 4;
      int c0 = colBase + wc*64 + ni*16 + (lane & 15);
      #pragma unroll
      for (int q = 0; q < 4; ++q)
        C[(size_t)(r0 + q) * ldc + c0] = f2bf(acc[mi][ni][q]);
    }
  }
}

// ---------------- big GEMM: Y[8192,4096] = U[8192,1024] @ Mcat[4096,1024]^T -
// LDS (ushort offsets): A_k0 @0, A_k1 @8192, B_k0 @16384, B_k1 @24576.
// Fragment-major half-tile: (row,kk<32) -> rg*512 + kq*128 + rsel*8 (ushorts).
// STAGE: dest c_*16B linear; global source decoded from c_:
//   rsel=c_&15, kq=(c_>>4)&3, rg=c_>>6  ->  row=rg*16+rsel, kslot=kq*8
#define STAGE_HALF(GB, LOFF)                                                   \
  { _Pragma("unroll")                                                          \
    for (int i_ = 0; i_ < 2; ++i_){                                            \
      int c_ = tid + i_*512;                                                   \
      int row_ = ((c_ >> 6) << 4) + (c_ & 15);                                 \
      int ks_  = ((c_ >> 4) & 3) * 8;                                          \
      const ushort* g_ = (GB) + (size_t)row_ * 1024 + ks_;                     \
      __builtin_amdgcn_global_load_lds(                                        \
        (const __attribute__((address_space(1))) void*)g_,                     \
        (__attribute__((address_space(3))) void*)&lds[(LOFF) + c_*8],          \
        16, 0, 0);                                                             \
    } }

// wave read: base + lane*8 ushorts (= lane*16 B), rg folded as imm offset
#define LOAD_A4(DST, KH, MH)                                                   \
  { _Pragma("unroll")                                                          \
    for (int mi_ = 0; mi_ < 4; ++mi_){                                         \
      int rg_ = wm*8 + (MH)*4 + mi_;                                           \
      DST[mi_] = *(const bf16x8*)&lds[cbase + (KH)*8192 + rg_*512 + lane*8];   \
    } }

#define LOAD_B4(DST, KH)                                                       \
  { _Pragma("unroll")                                                          \
    for (int ni_ = 0; ni_ < 4; ++ni_){                                         \
      int rg_ = wn*4 + ni_;                                                    \
      DST[ni_] = *(const bf16x8*)&lds[cbase + 16384 + (KH)*8192 + rg_*512 + lane*8]; \
    } }

#define MFMA16(MH, AARR, BARR)                                                 \
  { _Pragma("unroll")                                                          \
    for (int mi_ = 0; mi_ < 4; ++mi_)                                          \
      { _Pragma("unroll")                                                      \
        for (int ni_ = 0; ni_ < 4; ++ni_)                                      \
          acc[(MH)*4+mi_][ni_] = __builtin_amdgcn_mfma_f32_16x16x32_bf16(      \
              AARR[mi_], BARR[ni_], acc[(MH)*4+mi_][ni_], 0, 0, 0); } }

#define BAR() __builtin_amdgcn_s_barrier()

__global__ __launch_bounds__(512, 2) void gemm_big(const ushort* __restrict__ A,
                                                   const ushort* __restrict__ B,
                                                   ushort* __restrict__ C,
                                                   const float* __restrict__ dlog,
                                                   float* __restrict__ carry){
  __shared__ ushort lds[65536];       // 128 KB -> 1 block/CU
  const int tid  = threadIdx.x;
  const int lane = tid & 63;
  const int w    = tid >> 6;          // 0..7
  const int wm   = w >> 2;            // 2 M-waves
  const int wn   = w & 3;             // 4 N-waves
  const int rsel = lane & 15;

  // XCD region map: 8Mx8N tile region per XCD (per-XCD footprint 4+4 MB).
  int bid = blockIdx.x;
  int xcd = bid & 7, rr = bid >> 3;   // rr in 0..63
  const int rowBase = (((xcd >> 1) << 3) + (rr & 7)) * 256;   // 32 M-tiles
  const int colBase = (((xcd & 1) << 3) + (rr >> 3)) * 256;   // 16 N-tiles

  const ushort* Ag = A + (size_t)rowBase * 1024;
  const ushort* Bg = B + (size_t)colBase * 1024;

  f32x4 acc[8][4] = {};

  // prologue: stage tile0 -> buf0, tile1 -> buf1; wait tile0 (8 outstanding).
  STAGE_HALF(Ag +  0, 0);
  STAGE_HALF(Bg +  0, 16384);
  STAGE_HALF(Ag + 32, 8192);
  STAGE_HALF(Bg + 32, 24576);
  STAGE_HALF(Ag + 64, 32768 + 0);
  STAGE_HALF(Bg + 64, 32768 + 16384);
  STAGE_HALF(Ag + 96, 32768 + 8192);
  STAGE_HALF(Bg + 96, 32768 + 24576);
  asm volatile("s_waitcnt vmcnt(8)" ::: "memory");
  BAR();

  for (int t = 0; t < 16; ++t){
    const int cbase = (t & 1) * 32768;
    bf16x8 am0[4], am1[4], bf0[4];
    // k-half 0: 12 ds_reads + 32 MFMA (compiler interleaves, fine lgkmcnt)
    LOAD_A4(am0, 0, 0); LOAD_B4(bf0, 0); LOAD_A4(am1, 0, 1);
    MFMA16(0, am0, bf0);
    MFMA16(1, am1, bf0);
    // k-half 1
    LOAD_A4(am0, 1, 0); LOAD_B4(bf0, 1); LOAD_A4(am1, 1, 1);
    MFMA16(0, am0, bf0);
    MFMA16(1, am1, bf0);
    // all this wave's reads of buf(cbase) complete before signaling
    asm volatile("s_waitcnt lgkmcnt(0)" ::: "memory");
    BAR();
    // overwrite buf(cbase) with tile t+2; ensure tile t+1 landed (counted)
    if (t < 14){
      STAGE_HALF(Ag + (t+2)*64,      cbase + 0);
      STAGE_HALF(Bg + (t+2)*64,      cbase + 16384);
      STAGE_HALF(Ag + (t+2)*64 + 32, cbase + 8192);
      STAGE_HALF(Bg + (t+2)*64 + 32, cbase + 24576);
      asm volatile("s_waitcnt vmcnt(8)" ::: "memory");
    } else {
      asm volatile("s_waitcnt vmcnt(0)" ::: "memory");
    }
    BAR();
  }

  // ---- epilogue: stage C tile (256x256 bf16 = 128KB) into LDS (32B-XOR
  // swizzle), fused per-chunk scan carries, coalesced 16B/lane Y stores.
  #pragma unroll
  for (int mi = 0; mi < 8; ++mi){
    #pragma unroll
    for (int j = 0; j < 4; ++j){
      #pragma unroll
      for (int q = 0; q < 4; ++q){
        int row = wm*128 + mi*16 + (lane >> 4)*4 + q;
        int col = wn*64 + j*16 + rsel;
        int byte = row*512 + col*2;
        byte ^= ((row >> 2) & 3) << 5;
        *(ushort*)((char*)lds + byte) = f2bf(acc[mi][j][q]);
      }
    }
  }
  __syncthreads();

  // fused scanA: carry over this tile's 4 chunks of 64 t
  {
    const int k_blk = colBase >> 10;
    const int b_blk = rowBase >> 11;
    const int ch0   = (rowBase & 2047) >> 6;
    const int d0    = colBase & 1023;
    const float p   = sigm(dlog[k_blk]);
    #pragma unroll
    for (int s = 0; s < 2; ++s){
      int task = tid + s*512;
      int col = task & 255, ch = task >> 8;     // 256 cols x 4 chunks
      float a = 0.f;
      for (int i = 0; i < 64; ++i){
        int row = ch*64 + i;
        int byte = row*512 + col*2;
        byte ^= ((row >> 2) & 3) << 5;
        a = p * a + bf2f(*(const ushort*)((char*)lds + byte));
      }
      carry[(size_t)((b_blk*Kk + k_blk)*NCH + ch0 + ch) * Dd + d0 + col] = a;
    }
  }

  // coalesced Y write: 16B per lane
  #pragma unroll
  for (int j = 0; j < 16; ++j){
    int idx = tid + j*512;            // 0..8191
    int r = idx >> 5, c8 = idx & 31;
    int byte = r*512 + c8*16;
    byte ^= ((r >> 2) & 3) << 5;
    f32x4 v = *(const f32x4*)((char*)lds + byte);
    *(f32x4*)&C[(size_t)(rowBase + r) * Ee + colBase + c8*8] = v;
  }
}

// ---------------- wave-per-output dot kernels (fp32) ------------------------
__global__ __launch_bounds__(256) void k_z0(const float* __restrict__ Wout,
                                            const float* __restrict__ s0,
                                            float* __restrict__ z0){
  int gid  = blockIdx.x * 4 + (threadIdx.x >> 6);
  int lane = threadIdx.x & 63;
  int d = gid & 1023, k = (gid >> 10) & 3, b = gid >> 12;
  const float* wrow = Wout + (size_t)d * Ee + k * Dd;
  const float* sv   = s0 + ((size_t)(b*Kk + k) << 10);
  float s = 0.f;
  #pragma unroll
  for (int j = 0; j < 16; ++j) s += wrow[lane + j*64] * sv[lane + j*64];
  for (int off = 32; off; off >>= 1) s += __shfl_down(s, off);
  if (lane == 0) z0[gid] = s;
}

__global__ __launch_bounds__(256) void k_cterm(const float* __restrict__ Wout,
                                               const float* __restrict__ b_in,
                                               float* __restrict__ cterm){
  int gid  = blockIdx.x * 4 + (threadIdx.x >> 6);
  int lane = threadIdx.x & 63;
  int d = gid & 1023, k = gid >> 10;
  const float* wrow = Wout + (size_t)d * Ee + k * Dd;
  const float* bv   = b_in + k * Dd;
  float s = 0.f;
  #pragma unroll
  for (int j = 0; j < 16; ++j) s += wrow[lane + j*64] * bv[lane + j*64];
  for (int off = 32; off; off >>= 1) s += __shfl_down(s, off);
  if (lane == 0) cterm[gid] = s;
}

__global__ __launch_bounds__(256) void k_scanInc(const float* __restrict__ carry,
                                                 const float* __restrict__ z0,
                                                 const float* __restrict__ dlog,
                                                 float* __restrict__ incoming){
  int idx = blockIdx.x * 256 + threadIdx.x;
  int k = (idx >> 10) & 3;
  int bk = idx >> 10, d = idx & 1023;
  float p  = sigm(dlog[k]);
  float dL = powf(p, (float)LCH);
  float inc = z0[idx];
  for (int c = 0; c < NCH; ++c){
    size_t o = ((size_t)(bk * NCH + c)) * Dd + d;
    incoming[o] = inc;
    inc = dL * inc + carry[o];
  }
}

__global__ __launch_bounds__(256) void k_scanB(const ushort* __restrict__ Y,
                                               const float* __restrict__ incoming,
                                               const float* __restrict__ dlog,
                                               const float* __restrict__ b_out,
                                               const float* __restrict__ cterm,
                                               float* __restrict__ g){
  int x = blockIdx.x;
  int d = blockIdx.y * 256 + threadIdx.x;
  int c = x & 31, b = x >> 5;
  float p[4], z[4], ct[4], pw[4];
  #pragma unroll
  for (int k = 0; k < 4; ++k){
    p[k]  = sigm(dlog[k]);
    z[k]  = incoming[((size_t)(((b*Kk + k))*NCH + c)) * Dd + d];
    float omp = fmaxf(1.0f - p[k], 1e-30f);
    ct[k] = cterm[k * Dd + d] / omp;
    pw[k] = powf(p[k], (float)(c * LCH + 1));
  }
  float bo = b_out[d];
  size_t ybase = ((size_t)(b*Tt + c*LCH)) * Ee + d;
  size_t gbase = ((size_t)(b*Tt + c*LCH)) * Dd + d;
  for (int i = 0; i < LCH; ++i){
    float acc = bo;
    #pragma unroll
    for (int k = 0; k < 4; ++k){
      z[k] = p[k] * z[k] + bf2f(Y[ybase + (size_t)k * Dd]);
      acc += z[k] + ct[k] * (1.0f - pw[k]);
      pw[k] *= p[k];
    }
    g[gbase] = acc;
    ybase += Ee; gbase += Dd;
  }
}

// ---------------- v path (+ fused u -> bf16 conversion) ---------------------
__global__ __launch_bounds__(256) void k_prep(const float* __restrict__ u,
                                              const float* __restrict__ dlog,
                                              float* __restrict__ vpart,
                                              ushort* __restrict__ U_bf){
  int x = blockIdx.x;                    // b*NCH + c
  int d = blockIdx.y * 256 + threadIdx.x;
  int c = x & 31, b = x >> 5;
  float p[4], a[4] = {0.f, 0.f, 0.f, 0.f};
  #pragma unroll
  for (int k = 0; k < 4; ++k) p[k] = sigm(dlog[k]);
  size_t ub = ((size_t)(b*Tt + c*LCH)) * Dd + d;
  for (int i = 0; i < LCH; ++i){
    float uv = u[ub];
    U_bf[ub] = f2bf(uv);
    #pragma unroll
    for (int k = 0; k < 4; ++k) a[k] = p[k] * a[k] + uv;
    ub += Dd;
  }
  #pragma unroll
  for (int k = 0; k < 4; ++k)
    vpart[(((size_t)x) * Kk + k) * Dd + d] = a[k];
}

__global__ __launch_bounds__(256) void k_vcomb(const float* __restrict__ vpart,
                                               const float* __restrict__ dlog,
                                               float* __restrict__ vfull){
  int idx = blockIdx.x * 256 + threadIdx.x;
  int k = (idx >> 10) & 3, b = idx >> 12, d = idx & 1023;
  float p  = sigm(dlog[k]);
  float dL = powf(p, (float)LCH);
  float v = 0.f;
  for (int c = 0; c < NCH; ++c)
    v = dL * v + vpart[(((size_t)(b*NCH + c)) * Kk + k) * Dd + d];
  vfull[idx] = v;
}

__global__ __launch_bounds__(256) void k_slast(const float* __restrict__ W_in,
                                               const float* __restrict__ vfull,
                                               const float* __restrict__ s0,
                                               const float* __restrict__ b_in,
                                               const float* __restrict__ dlog,
                                               float* __restrict__ out){
  int gid  = blockIdx.x * 4 + (threadIdx.x >> 6);
  int lane = threadIdx.x & 63;
  int d = gid & 1023, k = (gid >> 10) & 3, b = gid >> 12;
  const float* wrow = W_in + (size_t)(k*Dd + d) * Dd;
  const float* vv   = vfull + ((size_t)(b*Kk + k) << 10);
  float s = 0.f;
  #pragma unroll
  for (int j = 0; j < 16; ++j) s += wrow[lane + j*64] * vv[lane + j*64];
  for (int off = 32; off; off >>= 1) s += __shfl_down(s, off);
  if (lane == 0){
    float p  = sigm(dlog[k]);
    float pT = powf(p, (float)Tt);
    float omp = 1.0f - p;
    float geo = (omp < 1e-12f) ? (float)Tt : (1.0f - pT) / omp;
    out[gid] = pT * s0[gid] + s + b_in[k*Dd + d] * geo;
  }
}

// ---------------------------------------------------------------------------
extern "C" void kernel_launch(void* const* d_in, const int* in_sizes, int n_in,
                              void* d_out, int out_size, void* d_ws, size_t ws_size,
                              hipStream_t stream){
  const float* u     = (const float*)d_in[0];
  const float* s0    = (const float*)d_in[1];
  const float* W_in  = (const float*)d_in[2];
  const float* b_in  = (const float*)d_in[3];
  const float* W_out = (const float*)d_in[4];
  const float* b_out = (const float*)d_in[5];
  const float* dlog  = (const float*)d_in[6];

  float* g_out     = (float*)d_out;                      // B*T*D
  float* slast_out = g_out + (size_t)BT * Dd;            // B*K*D

  char* ws = (char*)d_ws;
  if (ws_size < 115490816ull) return;
  ushort* U_bf    = (ushort*)(ws);                       // 16 MB
  ushort* WinT    = (ushort*)(ws + 16777216);            //  8 MB
  ushort* Wout_bf = (ushort*)(ws + 25165824);            //  8 MB
  ushort* Mcat    = (ushort*)(ws + 33554432);            //  8 MB
  ushort* Y       = (ushort*)(ws + 41943040);            // 64 MB
  float*  carry   = (float*)(ws + 109051904);            //  2 MB
  float*  incoming= (float*)(ws + 111149056);            //  2 MB
  float*  z0buf   = (float*)(ws + 113246208);            // 64 KB
  float*  cterm   = (float*)(ws + 113311744);            // 16 KB
  float*  vpart   = (float*)(ws + 113328128);            //  2 MB
  float*  vfull   = (float*)(ws + 115425280);            // 64 KB

  // prep: u -> U_bf (fused) + vpart; weight converts
  k_prep<<<dim3(128, 4), 256, 0, stream>>>(u, dlog, vpart, U_bf);
  k_f2bf4<<<4096, 256, 0, stream>>>((const float4*)W_out, (ushort4*)Wout_bf, Dd*Ee/4);
  k_transpose<<<dim3(32, 128), dim3(32, 8), 0, stream>>>(W_in, WinT);

  // Mcat[(k,d), d'] = sum_j Wout[d, kD+j] * WinT[d', kD+j]
  gemm_nt<<<dim3(8, 8, 4), 256, 0, stream>>>(Wout_bf, WinT, Mcat,
                                             1024, Ee, Ee, Dd,
                                             1024L, 1024L, 1048576L);
  // Y = U @ Mcat^T, free-running 256^2, conflict-free fragment-major LDS
  gemm_big<<<512, 512, 0, stream>>>(U_bf, Mcat, Y, dlog, carry);

  // scan-init terms
  k_z0<<<4096, 256, 0, stream>>>(W_out, s0, z0buf);
  k_cterm<<<1024, 256, 0, stream>>>(W_out, b_in, cterm);

  // cross-chunk scan + apply
  k_scanInc<<<64, 256, 0, stream>>>(carry, z0buf, dlog, incoming);
  k_scanB<<<dim3(128, 4), 256, 0, stream>>>(Y, incoming, dlog, b_out, cterm, g_out);

  // s_last path
  k_vcomb<<<64, 256, 0, stream>>>(vpart, dlog, vfull);
  k_slast<<<4096, 256, 0, stream>>>(W_in, vfull, s0, b_in, dlog, slast_out);
}

// Round 10
// 173.683 us; speedup vs baseline: 1.0895x; 1.0895x over previous
//
#include <hip/hip_runtime.h>

// ---------------------------------------------------------------------------
// StateBank: g = W_out @ scan(W_in @ u), restructured as
//   M_k = W_out_k @ W_in_k  (composite, k=0..3, each 1024x1024)
//   Y[b,t,(k,d)] = sum_d' M_k[d,d'] u[b,t,d']       (one 8192x4096x1024 GEMM)
//   z_k / g via chunked parallel scan; s_last via weighted time-reduction.
// Big GEMM (R10): 128x128 tile, 4 waves, BK=32, 32KB double-buffer ->
// 4 blocks/CU (16 waves/CU). Free-running K-interior (R8 schedule), counted
// vmcnt(4), R8 staging (coalesced source + 16B-slot XOR). Cross-BLOCK overlap
// hides staging latency + epilogue (R4-R9 plateau was 1 block/CU, no overlap).
// Epilogue: 32KB C-stage in LDS (XOR (row&3)^((row>>2)&3)), fused carries,
// coalesced Y stores. Aux: z0/cterm read Wout_bf (bf16, vectorized).
// ---------------------------------------------------------------------------

#define Bb 4
#define Tt 2048
#define Dd 1024
#define Kk 4
#define BT (Bb*Tt)          // 8192
#define Ee (Kk*Dd)          // 4096
#define NCH 32              // scan chunks
#define LCH 64              // chunk length (NCH*LCH = T)

typedef __bf16 bf16x8 __attribute__((ext_vector_type(8)));
typedef float  f32x4  __attribute__((ext_vector_type(4)));

__device__ __forceinline__ float bf2f(ushort u){
  union { unsigned int i; float f; } x; x.i = ((unsigned int)u) << 16; return x.f;
}
__device__ __forceinline__ ushort f2bf(float f){
  union { unsigned int i; float f; } x; x.f = f;
  unsigned int i = x.i;
  return (ushort)((i + 0x7FFFu + ((i >> 16) & 1u)) >> 16);   // RNE
}
__device__ __forceinline__ float lo16(unsigned u){
  union { unsigned i; float f; } x; x.i = u << 16; return x.f;
}
__device__ __forceinline__ float hi16(unsigned u){
  union { unsigned i; float f; } x; x.i = u & 0xFFFF0000u; return x.f;
}
__device__ __forceinline__ float sigm(float x){ return 1.0f / (1.0f + expf(-x)); }

// ---------------- convert f32 -> bf16 (vectorized) ----------------
__global__ __launch_bounds__(256) void k_f2bf4(const float4* __restrict__ in,
                                               ushort4* __restrict__ out, int n4){
  int i = blockIdx.x * 256 + threadIdx.x;
  if (i < n4){
    float4 v = in[i];
    ushort4 o; o.x = f2bf(v.x); o.y = f2bf(v.y); o.z = f2bf(v.z); o.w = f2bf(v.w);
    out[i] = o;
  }
}

// ---------------- transpose W_in (4096x1024 f32) -> WinT (1024x4096 bf16) ---
__global__ __launch_bounds__(256) void k_transpose(const float* __restrict__ in,
                                                   ushort* __restrict__ out){
  __shared__ float tile[32][33];
  int tx = threadIdx.x, ty = threadIdx.y;          // 32 x 8
  int c0 = blockIdx.x * 32, r0 = blockIdx.y * 32;
  #pragma unroll
  for (int j = 0; j < 4; ++j)
    tile[ty + j*8][tx] = in[(size_t)(r0 + ty + j*8) * Dd + c0 + tx];
  __syncthreads();
  #pragma unroll
  for (int j = 0; j < 4; ++j)
    out[(size_t)(c0 + ty + j*8) * Ee + r0 + tx] = f2bf(tile[tx][ty + j*8]);
}

// ---------------- small NT GEMM (m97 structure) for Mcat --------------------
__global__ __launch_bounds__(256) void gemm_nt(const ushort* __restrict__ A,
                                               const ushort* __restrict__ B,
                                               ushort* __restrict__ C,
                                               int Kred, int lda, int ldb, int ldc,
                                               long aBatch, long bBatch, long cBatch){
  __shared__ ushort As[128 * 32];
  __shared__ ushort Bs[128 * 32];
  A += (long)blockIdx.z * aBatch;
  B += (long)blockIdx.z * bBatch;
  C += (long)blockIdx.z * cBatch;
  const int tid  = threadIdx.x;
  const int lane = tid & 63;
  const int w    = tid >> 6;
  const int wr   = w >> 1, wc = w & 1;
  const int rowBase = blockIdx.x * 128;
  const int colBase = blockIdx.y * 128;

  f32x4 acc[4][4] = {};
  const int krow = (lane >> 4) * 8;
  const int rsel = lane & 15;

  for (int kk = 0; kk < Kred; kk += 32){
    __syncthreads();
    #pragma unroll
    for (int i = 0; i < 2; ++i){
      int c  = i * 256 + tid;
      int r  = c >> 2;
      int c8 = (c & 3) * 8;
      const ushort* ga = A + (size_t)(rowBase + r) * lda + kk + c8;
      const ushort* gb = B + (size_t)(colBase + r) * ldb + kk + c8;
      __builtin_amdgcn_global_load_lds((const __attribute__((address_space(1))) void*)ga,
                                       (__attribute__((address_space(3))) void*)&As[c * 8],
                                       16, 0, 0);
      __builtin_amdgcn_global_load_lds((const __attribute__((address_space(1))) void*)gb,
                                       (__attribute__((address_space(3))) void*)&Bs[c * 8],
                                       16, 0, 0);
    }
    asm volatile("s_waitcnt vmcnt(0)" ::: "memory");
    __syncthreads();

    bf16x8 Af[4], Bf[4];
    #pragma unroll
    for (int mi = 0; mi < 4; ++mi)
      Af[mi] = *(const bf16x8*)&As[(wr*64 + mi*16 + rsel) * 32 + krow];
    #pragma unroll
    for (int ni = 0; ni < 4; ++ni)
      Bf[ni] = *(const bf16x8*)&Bs[(wc*64 + ni*16 + rsel) * 32 + krow];
    #pragma unroll
    for (int mi = 0; mi < 4; ++mi)
      #pragma unroll
      for (int ni = 0; ni < 4; ++ni)
        acc[mi][ni] = __builtin_amdgcn_mfma_f32_16x16x32_bf16(Af[mi], Bf[ni], acc[mi][ni], 0, 0, 0);
  }

  #pragma unroll
  for (int mi = 0; mi < 4; ++mi){
    #pragma unroll
    for (int ni = 0; ni < 4; ++ni){
      int r0 = rowBase + wr*64 + mi*16 + (lane >> 4) * 4;
      int c0 = colBase + wc*64 + ni*16 + (lane & 15);
      #pragma unroll
      for (int q = 0; q < 4; ++q)
        C[(size_t)(r0 + q) * ldc + c0] = f2bf(acc[mi][ni][q]);
    }
  }
}

// ---------------- big GEMM: Y[8192,4096] = U[8192,1024] @ Mcat[4096,1024]^T -
// 128x128, 4 waves, BK=32. LDS: buf c @ c*8192 ushorts {A [128][32] @0,
// B [128][32] @4096}. Stage: dest linear, source slot XOR (R8 pattern).
#define STAGE_OP(GB, LOFF)                                                     \
  { _Pragma("unroll")                                                          \
    for (int i_ = 0; i_ < 2; ++i_){                                            \
      int c_ = tid + i_*256;                                                   \
      int row_ = c_ >> 2;                                                      \
      int ss_ = (c_ & 3) ^ ((row_ >> 2) & 3);                                  \
      const ushort* g_ = (GB) + (size_t)row_ * 1024 + ss_ * 8;                 \
      __builtin_amdgcn_global_load_lds(                                        \
        (const __attribute__((address_space(1))) void*)g_,                     \
        (__attribute__((address_space(3))) void*)&lds[(LOFF) + c_*8],          \
        16, 0, 0);                                                             \
    } }

#define LOAD_A4(DST)                                                           \
  { _Pragma("unroll")                                                          \
    for (int mi_ = 0; mi_ < 4; ++mi_){                                         \
      int r_ = wm*64 + mi_*16 + rsel;                                          \
      int uo_ = r_*32 + kq*8;                                                  \
      uo_ ^= ((uo_ >> 7) & 3) << 3;                                            \
      DST[mi_] = *(const bf16x8*)&lds[cbase + uo_];                            \
    } }

#define LOAD_B4(DST)                                                           \
  { _Pragma("unroll")                                                          \
    for (int ni_ = 0; ni_ < 4; ++ni_){                                         \
      int r_ = wn*64 + ni_*16 + rsel;                                          \
      int uo_ = r_*32 + kq*8;                                                  \
      uo_ ^= ((uo_ >> 7) & 3) << 3;                                            \
      DST[ni_] = *(const bf16x8*)&lds[cbase + 4096 + uo_];                     \
    } }

#define XB(R) ((((R) & 3) ^ (((R) >> 2) & 3)) << 5)
#define BAR() __builtin_amdgcn_s_barrier()

__global__ __launch_bounds__(256, 4) void gemm_big(const ushort* __restrict__ A,
                                                   const ushort* __restrict__ B,
                                                   ushort* __restrict__ C,
                                                   const float* __restrict__ dlog,
                                                   float* __restrict__ carry){
  __shared__ ushort lds[16384];       // 32 KB -> 4 blocks/CU
  const int tid  = threadIdx.x;
  const int lane = tid & 63;
  const int w    = tid >> 6;          // 0..3
  const int wm   = w >> 1;            // 2 M-waves
  const int wn   = w & 1;             // 2 N-waves
  const int rsel = lane & 15;
  const int kq   = lane >> 4;

  // XCD region map: grid 64Mx32N tiles; each XCD owns a 16x16-tile region.
  int bid = blockIdx.x;
  int xcd = bid & 7, rr = bid >> 3;   // rr 0..255
  const int rowBase = ((xcd >> 1) * 16 + (rr & 15)) * 128;   // 64 M-tiles
  const int colBase = ((xcd & 1) * 16 + (rr >> 4)) * 128;    // 32 N-tiles

  const ushort* Ag = A + (size_t)rowBase * 1024;
  const ushort* Bg = B + (size_t)colBase * 1024;

  f32x4 acc[4][4] = {};

  // prologue: tile0 -> buf0, tile1 -> buf1 (4 loads/thread each)
  STAGE_OP(Ag +  0, 0);
  STAGE_OP(Bg +  0, 4096);
  STAGE_OP(Ag + 32, 8192);
  STAGE_OP(Bg + 32, 8192 + 4096);
  asm volatile("s_waitcnt vmcnt(4)" ::: "memory");   // tile0 landed
  BAR();

  for (int t = 0; t < 32; ++t){
    const int cbase = (t & 1) * 8192;
    bf16x8 af[4], bf[4];
    LOAD_A4(af); LOAD_B4(bf);
    #pragma unroll
    for (int mi = 0; mi < 4; ++mi)
      #pragma unroll
      for (int ni = 0; ni < 4; ++ni)
        acc[mi][ni] = __builtin_amdgcn_mfma_f32_16x16x32_bf16(af[mi], bf[ni], acc[mi][ni], 0, 0, 0);
    asm volatile("s_waitcnt lgkmcnt(0)" ::: "memory");
    BAR();
    if (t < 30){
      STAGE_OP(Ag + (t+2)*32, cbase);
      STAGE_OP(Bg + (t+2)*32, cbase + 4096);
      asm volatile("s_waitcnt vmcnt(4)" ::: "memory");   // tile t+1 landed
    } else {
      asm volatile("s_waitcnt vmcnt(0)" ::: "memory");
    }
    BAR();
  }

  // ---- epilogue: C tile (128x128 bf16 = 32KB) into LDS with XB row-XOR,
  // fused per-chunk scan carries (b32 col-pairs), coalesced 16B Y stores.
  #pragma unroll
  for (int mi = 0; mi < 4; ++mi){
    #pragma unroll
    for (int j = 0; j < 4; ++j){
      #pragma unroll
      for (int q = 0; q < 4; ++q){
        int row = wm*64 + mi*16 + (lane >> 4)*4 + q;
        int col = wn*64 + j*16 + rsel;
        int byte = (row*256 + col*2) ^ XB(row);
        *(ushort*)((char*)lds + byte) = f2bf(acc[mi][j][q]);
      }
    }
  }
  __syncthreads();

  // fused scanA: 2 chunks x 64 col-pairs -> threads 0..127
  if (tid < 128){
    const int k_blk = colBase >> 10;
    const int b_blk = rowBase >> 11;
    const int ch0   = (rowBase & 2047) >> 6;
    const int d0    = colBase & 1023;
    const float p   = sigm(dlog[k_blk]);
    int cp = tid & 63, ch = tid >> 6;
    float a0 = 0.f, a1 = 0.f;
    for (int i = 0; i < 64; ++i){
      int row = ch*64 + i;
      int byte = (row*256 + cp*4) ^ XB(row);
      unsigned v = *(const unsigned*)((char*)lds + byte);
      a0 = p * a0 + lo16(v);
      a1 = p * a1 + hi16(v);
    }
    float* cdst = &carry[(size_t)((b_blk*Kk + k_blk)*NCH + ch0 + ch) * Dd + d0 + cp*2];
    cdst[0] = a0; cdst[1] = a1;
  }

  // coalesced Y write: 16B per lane, 8 sweeps
  #pragma unroll
  for (int j = 0; j < 8; ++j){
    int idx = tid + j*256;            // 0..2047
    int r = idx >> 4, c16 = idx & 15;
    int byte = (r*256 + c16*16) ^ XB(r);
    f32x4 v = *(const f32x4*)((char*)lds + byte);
    *(f32x4*)&C[(size_t)(rowBase + r) * Ee + colBase + c16*8] = v;
  }
}

// ---------------- z0/cterm: bf16 weights, 16B/lane vector loads -------------
__global__ __launch_bounds__(256) void k_z0(const ushort* __restrict__ Wout_bf,
                                            const float* __restrict__ s0,
                                            float* __restrict__ z0){
  int gid  = blockIdx.x * 4 + (threadIdx.x >> 6);   // (b*K+k)*D + d
  int lane = threadIdx.x & 63;
  int d = gid & 1023, k = (gid >> 10) & 3, b = gid >> 12;
  const ushort* wrow = Wout_bf + (size_t)d * Ee + k * Dd;
  const float* sv   = s0 + ((size_t)(b*Kk + k) << 10);
  float s = 0.f;
  #pragma unroll
  for (int j = 0; j < 2; ++j){
    int base = lane*8 + j*512;
    uint4 wv = *(const uint4*)(wrow + base);
    float4 sa = *(const float4*)(sv + base);
    float4 sb = *(const float4*)(sv + base + 4);
    s += lo16(wv.x)*sa.x + hi16(wv.x)*sa.y + lo16(wv.y)*sa.z + hi16(wv.y)*sa.w
       + lo16(wv.z)*sb.x + hi16(wv.z)*sb.y + lo16(wv.w)*sb.z + hi16(wv.w)*sb.w;
  }
  for (int off = 32; off; off >>= 1) s += __shfl_down(s, off);
  if (lane == 0) z0[gid] = s;
}

__global__ __launch_bounds__(256) void k_cterm(const ushort* __restrict__ Wout_bf,
                                               const float* __restrict__ b_in,
                                               float* __restrict__ cterm){
  int gid  = blockIdx.x * 4 + (threadIdx.x >> 6);   // k*D + d
  int lane = threadIdx.x & 63;
  int d = gid & 1023, k = gid >> 10;
  const ushort* wrow = Wout_bf + (size_t)d * Ee + k * Dd;
  const float* bv   = b_in + k * Dd;
  float s = 0.f;
  #pragma unroll
  for (int j = 0; j < 2; ++j){
    int base = lane*8 + j*512;
    uint4 wv = *(const uint4*)(wrow + base);
    float4 sa = *(const float4*)(bv + base);
    float4 sb = *(const float4*)(bv + base + 4);
    s += lo16(wv.x)*sa.x + hi16(wv.x)*sa.y + lo16(wv.y)*sa.z + hi16(wv.y)*sa.w
       + lo16(wv.z)*sb.x + hi16(wv.z)*sb.y + lo16(wv.w)*sb.z + hi16(wv.w)*sb.w;
  }
  for (int off = 32; off; off >>= 1) s += __shfl_down(s, off);
  if (lane == 0) cterm[gid] = s;
}

__global__ __launch_bounds__(256) void k_scanInc(const float* __restrict__ carry,
                                                 const float* __restrict__ z0,
                                                 const float* __restrict__ dlog,
                                                 float* __restrict__ incoming){
  int idx = blockIdx.x * 256 + threadIdx.x;
  int k = (idx >> 10) & 3;
  int bk = idx >> 10, d = idx & 1023;
  float p  = sigm(dlog[k]);
  float dL = powf(p, (float)LCH);
  float inc = z0[idx];
  for (int c = 0; c < NCH; ++c){
    size_t o = ((size_t)(bk * NCH + c)) * Dd + d;
    incoming[o] = inc;
    inc = dL * inc + carry[o];
  }
}

__global__ __launch_bounds__(256) void k_scanB(const ushort* __restrict__ Y,
                                               const float* __restrict__ incoming,
                                               const float* __restrict__ dlog,
                                               const float* __restrict__ b_out,
                                               const float* __restrict__ cterm,
                                               float* __restrict__ g){
  int x = blockIdx.x;
  int d = blockIdx.y * 256 + threadIdx.x;
  int c = x & 31, b = x >> 5;
  float p[4], z[4], ct[4], pw[4];
  #pragma unroll
  for (int k = 0; k < 4; ++k){
    p[k]  = sigm(dlog[k]);
    z[k]  = incoming[((size_t)(((b*Kk + k))*NCH + c)) * Dd + d];
    float omp = fmaxf(1.0f - p[k], 1e-30f);
    ct[k] = cterm[k * Dd + d] / omp;
    pw[k] = powf(p[k], (float)(c * LCH + 1));
  }
  float bo = b_out[d];
  size_t ybase = ((size_t)(b*Tt + c*LCH)) * Ee + d;
  size_t gbase = ((size_t)(b*Tt + c*LCH)) * Dd + d;
  for (int i = 0; i < LCH; ++i){
    float acc = bo;
    #pragma unroll
    for (int k = 0; k < 4; ++k){
      z[k] = p[k] * z[k] + bf2f(Y[ybase + (size_t)k * Dd]);
      acc += z[k] + ct[k] * (1.0f - pw[k]);
      pw[k] *= p[k];
    }
    g[gbase] = acc;
    ybase += Ee; gbase += Dd;
  }
}

// ---------------- v path (+ fused u -> bf16 conversion) ---------------------
__global__ __launch_bounds__(256) void k_prep(const float* __restrict__ u,
                                              const float* __restrict__ dlog,
                                              float* __restrict__ vpart,
                                              ushort* __restrict__ U_bf){
  int x = blockIdx.x;                    // b*NCH + c
  int d = blockIdx.y * 256 + threadIdx.x;
  int c = x & 31, b = x >> 5;
  float p[4], a[4] = {0.f, 0.f, 0.f, 0.f};
  #pragma unroll
  for (int k = 0; k < 4; ++k) p[k] = sigm(dlog[k]);
  size_t ub = ((size_t)(b*Tt + c*LCH)) * Dd + d;
  for (int i = 0; i < LCH; ++i){
    float uv = u[ub];
    U_bf[ub] = f2bf(uv);
    #pragma unroll
    for (int k = 0; k < 4; ++k) a[k] = p[k] * a[k] + uv;
    ub += Dd;
  }
  #pragma unroll
  for (int k = 0; k < 4; ++k)
    vpart[(((size_t)x) * Kk + k) * Dd + d] = a[k];
}

__global__ __launch_bounds__(256) void k_vcomb(const float* __restrict__ vpart,
                                               const float* __restrict__ dlog,
                                               float* __restrict__ vfull){
  int idx = blockIdx.x * 256 + threadIdx.x;
  int k = (idx >> 10) & 3, b = idx >> 12, d = idx & 1023;
  float p  = sigm(dlog[k]);
  float dL = powf(p, (float)LCH);
  float v = 0.f;
  for (int c = 0; c < NCH; ++c)
    v = dL * v + vpart[(((size_t)(b*NCH + c)) * Kk + k) * Dd + d];
  vfull[idx] = v;
}

__global__ __launch_bounds__(256) void k_slast(const float* __restrict__ W_in,
                                               const float* __restrict__ vfull,
                                               const float* __restrict__ s0,
                                               const float* __restrict__ b_in,
                                               const float* __restrict__ dlog,
                                               float* __restrict__ out){
  int gid  = blockIdx.x * 4 + (threadIdx.x >> 6);
  int lane = threadIdx.x & 63;
  int d = gid & 1023, k = (gid >> 10) & 3, b = gid >> 12;
  const float* wrow = W_in + (size_t)(k*Dd + d) * Dd;
  const float* vv   = vfull + ((size_t)(b*Kk + k) << 10);
  float s = 0.f;
  #pragma unroll
  for (int j = 0; j < 16; ++j) s += wrow[lane + j*64] * vv[lane + j*64];
  for (int off = 32; off; off >>= 1) s += __shfl_down(s, off);
  if (lane == 0){
    float p  = sigm(dlog[k]);
    float pT = powf(p, (float)Tt);
    float omp = 1.0f - p;
    float geo = (omp < 1e-12f) ? (float)Tt : (1.0f - pT) / omp;
    out[gid] = pT * s0[gid] + s + b_in[k*Dd + d] * geo;
  }
}

// ---------------------------------------------------------------------------
extern "C" void kernel_launch(void* const* d_in, const int* in_sizes, int n_in,
                              void* d_out, int out_size, void* d_ws, size_t ws_size,
                              hipStream_t stream){
  const float* u     = (const float*)d_in[0];
  const float* s0    = (const float*)d_in[1];
  const float* W_in  = (const float*)d_in[2];
  const float* b_in  = (const float*)d_in[3];
  const float* W_out = (const float*)d_in[4];
  const float* b_out = (const float*)d_in[5];
  const float* dlog  = (const float*)d_in[6];

  float* g_out     = (float*)d_out;                      // B*T*D
  float* slast_out = g_out + (size_t)BT * Dd;            // B*K*D

  char* ws = (char*)d_ws;
  if (ws_size < 115490816ull) return;
  ushort* U_bf    = (ushort*)(ws);                       // 16 MB
  ushort* WinT    = (ushort*)(ws + 16777216);            //  8 MB
  ushort* Wout_bf = (ushort*)(ws + 25165824);            //  8 MB
  ushort* Mcat    = (ushort*)(ws + 33554432);            //  8 MB
  ushort* Y       = (ushort*)(ws + 41943040);            // 64 MB
  float*  carry   = (float*)(ws + 109051904);            //  2 MB
  float*  incoming= (float*)(ws + 111149056);            //  2 MB
  float*  z0buf   = (float*)(ws + 113246208);            // 64 KB
  float*  cterm   = (float*)(ws + 113311744);            // 16 KB
  float*  vpart   = (float*)(ws + 113328128);            //  2 MB
  float*  vfull   = (float*)(ws + 115425280);            // 64 KB

  // prep: u -> U_bf (fused) + vpart; weight converts
  k_prep<<<dim3(128, 4), 256, 0, stream>>>(u, dlog, vpart, U_bf);
  k_f2bf4<<<4096, 256, 0, stream>>>((const float4*)W_out, (ushort4*)Wout_bf, Dd*Ee/4);
  k_transpose<<<dim3(32, 128), dim3(32, 8), 0, stream>>>(W_in, WinT);

  // Mcat[(k,d), d'] = sum_j Wout[d, kD+j] * WinT[d', kD+j]
  gemm_nt<<<dim3(8, 8, 4), 256, 0, stream>>>(Wout_bf, WinT, Mcat,
                                             1024, Ee, Ee, Dd,
                                             1024L, 1024L, 1048576L);
  // Y = U @ Mcat^T: 128^2 tile, 4 blocks/CU, free-running, fused carries
  gemm_big<<<2048, 256, 0, stream>>>(U_bf, Mcat, Y, dlog, carry);

  // scan-init terms (bf16 weights)
  k_z0<<<4096, 256, 0, stream>>>(Wout_bf, s0, z0buf);
  k_cterm<<<1024, 256, 0, stream>>>(Wout_bf, b_in, cterm);

  // cross-chunk scan + apply
  k_scanInc<<<64, 256, 0, stream>>>(carry, z0buf, dlog, incoming);
  k_scanB<<<dim3(128, 4), 256, 0, stream>>>(Y, incoming, dlog, b_out, cterm, g_out);

  // s_last path
  k_vcomb<<<64, 256, 0, stream>>>(vpart, dlog, vfull);
  k_slast<<<4096, 256, 0, stream>>>(W_in, vfull, s0, b_in, dlog, slast_out);
}

// Round 11
// 167.321 us; speedup vs baseline: 1.1310x; 1.0380x over previous
//
#include <hip/hip_runtime.h>

// ---------------------------------------------------------------------------
// StateBank: g = W_out @ scan(W_in @ u):
//   M_k = W_out_k @ W_in_k; Y = U @ Mcat^T (8192x4096x1024 bf16 GEMM);
//   chunked scan -> g; s_last via weighted time-reduction.
// gemm_big (R11): R10 structure (128^2, 4 waves, BK=32, 4 blk/CU, free-run,
// counted vmcnt) with CORRECTED slot-XOR f(row)=(row>>1)&3: conflict-free
// fragment reads (f distinct over each even/odd rsel quad) AND coalesced
// staging (4 threads permute within one 64B window). R10's f=(row>>2)&3
// collided (8.39M conflict-cyc = +4/read); R9's conflict-free layout broke
// staging coalescing. This fixes both sides simultaneously.
// Tail: k_wout = fused W_out convert + z0 + cterm (one pass, -2 launches).
// ---------------------------------------------------------------------------

#define Bb 4
#define Tt 2048
#define Dd 1024
#define Kk 4
#define BT (Bb*Tt)          // 8192
#define Ee (Kk*Dd)          // 4096
#define NCH 32              // scan chunks
#define LCH 64              // chunk length (NCH*LCH = T)

typedef __bf16 bf16x8 __attribute__((ext_vector_type(8)));
typedef float  f32x4  __attribute__((ext_vector_type(4)));

__device__ __forceinline__ float bf2f(ushort u){
  union { unsigned int i; float f; } x; x.i = ((unsigned int)u) << 16; return x.f;
}
__device__ __forceinline__ ushort f2bf(float f){
  union { unsigned int i; float f; } x; x.f = f;
  unsigned int i = x.i;
  return (ushort)((i + 0x7FFFu + ((i >> 16) & 1u)) >> 16);   // RNE
}
__device__ __forceinline__ float lo16(unsigned u){
  union { unsigned i; float f; } x; x.i = u << 16; return x.f;
}
__device__ __forceinline__ float hi16(unsigned u){
  union { unsigned i; float f; } x; x.i = u & 0xFFFF0000u; return x.f;
}
__device__ __forceinline__ float sigm(float x){ return 1.0f / (1.0f + expf(-x)); }

// ---------------- transpose W_in (4096x1024 f32) -> WinT (1024x4096 bf16) ---
__global__ __launch_bounds__(256) void k_transpose(const float* __restrict__ in,
                                                   ushort* __restrict__ out){
  __shared__ float tile[32][33];
  int tx = threadIdx.x, ty = threadIdx.y;          // 32 x 8
  int c0 = blockIdx.x * 32, r0 = blockIdx.y * 32;
  #pragma unroll
  for (int j = 0; j < 4; ++j)
    tile[ty + j*8][tx] = in[(size_t)(r0 + ty + j*8) * Dd + c0 + tx];
  __syncthreads();
  #pragma unroll
  for (int j = 0; j < 4; ++j)
    out[(size_t)(c0 + ty + j*8) * Ee + r0 + tx] = f2bf(tile[tx][ty + j*8]);
}

// ---------------- fused W_out pass: bf16 convert + z0 + cterm ---------------
// wave = one (k,d): read W_out row f32 (coalesced float4), write Wout_bf,
// dot with b_in -> cterm, dot with s0[b] (b=0..3) -> z0.
__global__ __launch_bounds__(256) void k_wout(const float* __restrict__ Wout,
                                              const float* __restrict__ s0,
                                              const float* __restrict__ b_in,
                                              ushort* __restrict__ Wout_bf,
                                              float* __restrict__ z0,
                                              float* __restrict__ cterm){
  int gid  = blockIdx.x * 4 + (threadIdx.x >> 6);   // k*1024 + d  (0..4095)
  int lane = threadIdx.x & 63;
  int d = gid & 1023, k = gid >> 10;
  const float* wrow = Wout + (size_t)d * Ee + k * Dd;
  ushort*      wbf  = Wout_bf + (size_t)d * Ee + k * Dd;
  const float* bv   = b_in + k * Dd;
  float sc = 0.f, sz0 = 0.f, sz1 = 0.f, sz2 = 0.f, sz3 = 0.f;
  #pragma unroll
  for (int j = 0; j < 4; ++j){
    int base = lane*4 + j*256;
    float4 wv = *(const float4*)(wrow + base);
    ushort4 ob; ob.x = f2bf(wv.x); ob.y = f2bf(wv.y); ob.z = f2bf(wv.z); ob.w = f2bf(wv.w);
    *(ushort4*)(wbf + base) = ob;
    float4 bb = *(const float4*)(bv + base);
    sc += wv.x*bb.x + wv.y*bb.y + wv.z*bb.z + wv.w*bb.w;
    #pragma unroll
    for (int b = 0; b < 4; ++b){
      const float* sv = s0 + ((size_t)(b*Kk + k) << 10) + base;
      float4 s4 = *(const float4*)sv;
      float acc = wv.x*s4.x + wv.y*s4.y + wv.z*s4.z + wv.w*s4.w;
      if (b == 0) sz0 += acc; else if (b == 1) sz1 += acc;
      else if (b == 2) sz2 += acc; else sz3 += acc;
    }
  }
  for (int off = 32; off; off >>= 1){
    sc  += __shfl_down(sc, off);
    sz0 += __shfl_down(sz0, off);
    sz1 += __shfl_down(sz1, off);
    sz2 += __shfl_down(sz2, off);
    sz3 += __shfl_down(sz3, off);
  }
  if (lane == 0){
    cterm[gid] = sc;
    z0[gid]          = sz0;
    z0[gid + 4096]   = sz1;
    z0[gid + 8192]   = sz2;
    z0[gid + 12288]  = sz3;
  }
}

// ---------------- small NT GEMM (m97 structure) for Mcat --------------------
__global__ __launch_bounds__(256) void gemm_nt(const ushort* __restrict__ A,
                                               const ushort* __restrict__ B,
                                               ushort* __restrict__ C,
                                               int Kred, int lda, int ldb, int ldc,
                                               long aBatch, long bBatch, long cBatch){
  __shared__ ushort As[128 * 32];
  __shared__ ushort Bs[128 * 32];
  A += (long)blockIdx.z * aBatch;
  B += (long)blockIdx.z * bBatch;
  C += (long)blockIdx.z * cBatch;
  const int tid  = threadIdx.x;
  const int lane = tid & 63;
  const int w    = tid >> 6;
  const int wr   = w >> 1, wc = w & 1;
  const int rowBase = blockIdx.x * 128;
  const int colBase = blockIdx.y * 128;

  f32x4 acc[4][4] = {};
  const int krow = (lane >> 4) * 8;
  const int rsel = lane & 15;

  for (int kk = 0; kk < Kred; kk += 32){
    __syncthreads();
    #pragma unroll
    for (int i = 0; i < 2; ++i){
      int c  = i * 256 + tid;
      int r  = c >> 2;
      int c8 = (c & 3) * 8;
      const ushort* ga = A + (size_t)(rowBase + r) * lda + kk + c8;
      const ushort* gb = B + (size_t)(colBase + r) * ldb + kk + c8;
      __builtin_amdgcn_global_load_lds((const __attribute__((address_space(1))) void*)ga,
                                       (__attribute__((address_space(3))) void*)&As[c * 8],
                                       16, 0, 0);
      __builtin_amdgcn_global_load_lds((const __attribute__((address_space(1))) void*)gb,
                                       (__attribute__((address_space(3))) void*)&Bs[c * 8],
                                       16, 0, 0);
    }
    asm volatile("s_waitcnt vmcnt(0)" ::: "memory");
    __syncthreads();

    bf16x8 Af[4], Bf[4];
    #pragma unroll
    for (int mi = 0; mi < 4; ++mi)
      Af[mi] = *(const bf16x8*)&As[(wr*64 + mi*16 + rsel) * 32 + krow];
    #pragma unroll
    for (int ni = 0; ni < 4; ++ni)
      Bf[ni] = *(const bf16x8*)&Bs[(wc*64 + ni*16 + rsel) * 32 + krow];
    #pragma unroll
    for (int mi = 0; mi < 4; ++mi)
      #pragma unroll
      for (int ni = 0; ni < 4; ++ni)
        acc[mi][ni] = __builtin_amdgcn_mfma_f32_16x16x32_bf16(Af[mi], Bf[ni], acc[mi][ni], 0, 0, 0);
  }

  #pragma unroll
  for (int mi = 0; mi < 4; ++mi){
    #pragma unroll
    for (int ni = 0; ni < 4; ++ni){
      int r0 = rowBase + wr*64 + mi*16 + (lane >> 4) * 4;
      int c0 = colBase + wc*64 + ni*16 + (lane & 15);
      #pragma unroll
      for (int q = 0; q < 4; ++q)
        C[(size_t)(r0 + q) * ldc + c0] = f2bf(acc[mi][ni][q]);
    }
  }
}

// ---------------- big GEMM: Y[8192,4096] = U[8192,1024] @ Mcat[4096,1024]^T -
// 128x128, 4 waves, BK=32. LDS: buf c @ c*8192 ushorts {A@0, B@4096}.
// Slot XOR f(row)=(row>>1)&3: conflict-free reads + coalesced staging.
#define STAGE_OP(GB, LOFF)                                                     \
  { _Pragma("unroll")                                                          \
    for (int i_ = 0; i_ < 2; ++i_){                                            \
      int c_ = tid + i_*256;                                                   \
      int row_ = c_ >> 2;                                                      \
      int ss_ = (c_ & 3) ^ ((row_ >> 1) & 3);                                  \
      const ushort* g_ = (GB) + (size_t)row_ * 1024 + ss_ * 8;                 \
      __builtin_amdgcn_global_load_lds(                                        \
        (const __attribute__((address_space(1))) void*)g_,                     \
        (__attribute__((address_space(3))) void*)&lds[(LOFF) + c_*8],          \
        16, 0, 0);                                                             \
    } }

#define LOAD_A4(DST)                                                           \
  { _Pragma("unroll")                                                          \
    for (int mi_ = 0; mi_ < 4; ++mi_){                                         \
      int r_ = wm*64 + mi_*16 + rsel;                                          \
      int uo_ = r_*32 + kq*8;                                                  \
      uo_ ^= ((uo_ >> 6) & 3) << 3;                                            \
      DST[mi_] = *(const bf16x8*)&lds[cbase + uo_];                            \
    } }

#define LOAD_B4(DST)                                                           \
  { _Pragma("unroll")                                                          \
    for (int ni_ = 0; ni_ < 4; ++ni_){                                         \
      int r_ = wn*64 + ni_*16 + rsel;                                          \
      int uo_ = r_*32 + kq*8;                                                  \
      uo_ ^= ((uo_ >> 6) & 3) << 3;                                            \
      DST[ni_] = *(const bf16x8*)&lds[cbase + 4096 + uo_];                     \
    } }

#define XB(R) ((((R) & 3) ^ (((R) >> 2) & 3)) << 5)
#define BAR() __builtin_amdgcn_s_barrier()

__global__ __launch_bounds__(256, 4) void gemm_big(const ushort* __restrict__ A,
                                                   const ushort* __restrict__ B,
                                                   ushort* __restrict__ C,
                                                   const float* __restrict__ dlog,
                                                   float* __restrict__ carry){
  __shared__ ushort lds[16384];       // 32 KB -> 4 blocks/CU
  const int tid  = threadIdx.x;
  const int lane = tid & 63;
  const int w    = tid >> 6;          // 0..3
  const int wm   = w >> 1;            // 2 M-waves
  const int wn   = w & 1;             // 2 N-waves
  const int rsel = lane & 15;
  const int kq   = lane >> 4;

  // XCD region map: grid 64Mx32N tiles; each XCD owns a 16x16-tile region.
  int bid = blockIdx.x;
  int xcd = bid & 7, rr = bid >> 3;   // rr 0..255
  const int rowBase = ((xcd >> 1) * 16 + (rr & 15)) * 128;   // 64 M-tiles
  const int colBase = ((xcd & 1) * 16 + (rr >> 4)) * 128;    // 32 N-tiles

  const ushort* Ag = A + (size_t)rowBase * 1024;
  const ushort* Bg = B + (size_t)colBase * 1024;

  f32x4 acc[4][4] = {};

  // prologue: tile0 -> buf0, tile1 -> buf1 (4 loads/thread each)
  STAGE_OP(Ag +  0, 0);
  STAGE_OP(Bg +  0, 4096);
  STAGE_OP(Ag + 32, 8192);
  STAGE_OP(Bg + 32, 8192 + 4096);
  asm volatile("s_waitcnt vmcnt(4)" ::: "memory");   // tile0 landed
  BAR();

  for (int t = 0; t < 32; ++t){
    const int cbase = (t & 1) * 8192;
    bf16x8 af[4], bf[4];
    LOAD_A4(af); LOAD_B4(bf);
    #pragma unroll
    for (int mi = 0; mi < 4; ++mi)
      #pragma unroll
      for (int ni = 0; ni < 4; ++ni)
        acc[mi][ni] = __builtin_amdgcn_mfma_f32_16x16x32_bf16(af[mi], bf[ni], acc[mi][ni], 0, 0, 0);
    asm volatile("s_waitcnt lgkmcnt(0)" ::: "memory");
    BAR();
    if (t < 30){
      STAGE_OP(Ag + (t+2)*32, cbase);
      STAGE_OP(Bg + (t+2)*32, cbase + 4096);
      asm volatile("s_waitcnt vmcnt(4)" ::: "memory");   // tile t+1 landed
    } else {
      asm volatile("s_waitcnt vmcnt(0)" ::: "memory");
    }
    BAR();
  }

  // ---- epilogue: C tile (128x128 bf16 = 32KB) into LDS with XB row-XOR,
  // fused per-chunk scan carries (b32 col-pairs), coalesced 16B Y stores.
  #pragma unroll
  for (int mi = 0; mi < 4; ++mi){
    #pragma unroll
    for (int j = 0; j < 4; ++j){
      #pragma unroll
      for (int q = 0; q < 4; ++q){
        int row = wm*64 + mi*16 + (lane >> 4)*4 + q;
        int col = wn*64 + j*16 + rsel;
        int byte = (row*256 + col*2) ^ XB(row);
        *(ushort*)((char*)lds + byte) = f2bf(acc[mi][j][q]);
      }
    }
  }
  __syncthreads();

  // fused scanA: 2 chunks x 64 col-pairs -> threads 0..127
  if (tid < 128){
    const int k_blk = colBase >> 10;
    const int b_blk = rowBase >> 11;
    const int ch0   = (rowBase & 2047) >> 6;
    const int d0    = colBase & 1023;
    const float p   = sigm(dlog[k_blk]);
    int cp = tid & 63, ch = tid >> 6;
    float a0 = 0.f, a1 = 0.f;
    for (int i = 0; i < 64; ++i){
      int row = ch*64 + i;
      int byte = (row*256 + cp*4) ^ XB(row);
      unsigned v = *(const unsigned*)((char*)lds + byte);
      a0 = p * a0 + lo16(v);
      a1 = p * a1 + hi16(v);
    }
    float* cdst = &carry[(size_t)((b_blk*Kk + k_blk)*NCH + ch0 + ch) * Dd + d0 + cp*2];
    cdst[0] = a0; cdst[1] = a1;
  }

  // coalesced Y write: 16B per lane, 8 sweeps
  #pragma unroll
  for (int j = 0; j < 8; ++j){
    int idx = tid + j*256;            // 0..2047
    int r = idx >> 4, c16 = idx & 15;
    int byte = (r*256 + c16*16) ^ XB(r);
    f32x4 v = *(const f32x4*)((char*)lds + byte);
    *(f32x4*)&C[(size_t)(rowBase + r) * Ee + colBase + c16*8] = v;
  }
}

__global__ __launch_bounds__(256) void k_scanInc(const float* __restrict__ carry,
                                                 const float* __restrict__ z0,
                                                 const float* __restrict__ dlog,
                                                 float* __restrict__ incoming){
  int idx = blockIdx.x * 256 + threadIdx.x;
  int k = (idx >> 10) & 3;
  int bk = idx >> 10, d = idx & 1023;
  float p  = sigm(dlog[k]);
  float dL = powf(p, (float)LCH);
  float inc = z0[idx];
  for (int c = 0; c < NCH; ++c){
    size_t o = ((size_t)(bk * NCH + c)) * Dd + d;
    incoming[o] = inc;
    inc = dL * inc + carry[o];
  }
}

__global__ __launch_bounds__(256) void k_scanB(const ushort* __restrict__ Y,
                                               const float* __restrict__ incoming,
                                               const float* __restrict__ dlog,
                                               const float* __restrict__ b_out,
                                               const float* __restrict__ cterm,
                                               float* __restrict__ g){
  int x = blockIdx.x;
  int d = blockIdx.y * 256 + threadIdx.x;
  int c = x & 31, b = x >> 5;
  float p[4], z[4], ct[4], pw[4];
  #pragma unroll
  for (int k = 0; k < 4; ++k){
    p[k]  = sigm(dlog[k]);
    z[k]  = incoming[((size_t)(((b*Kk + k))*NCH + c)) * Dd + d];
    float omp = fmaxf(1.0f - p[k], 1e-30f);
    ct[k] = cterm[k * Dd + d] / omp;
    pw[k] = powf(p[k], (float)(c * LCH + 1));
  }
  float bo = b_out[d];
  size_t ybase = ((size_t)(b*Tt + c*LCH)) * Ee + d;
  size_t gbase = ((size_t)(b*Tt + c*LCH)) * Dd + d;
  for (int i = 0; i < LCH; ++i){
    float acc = bo;
    #pragma unroll
    for (int k = 0; k < 4; ++k){
      z[k] = p[k] * z[k] + bf2f(Y[ybase + (size_t)k * Dd]);
      acc += z[k] + ct[k] * (1.0f - pw[k]);
      pw[k] *= p[k];
    }
    g[gbase] = acc;
    ybase += Ee; gbase += Dd;
  }
}

// ---------------- v path (+ fused u -> bf16 conversion) ---------------------
__global__ __launch_bounds__(256) void k_prep(const float* __restrict__ u,
                                              const float* __restrict__ dlog,
                                              float* __restrict__ vpart,
                                              ushort* __restrict__ U_bf){
  int x = blockIdx.x;                    // b*NCH + c
  int d = blockIdx.y * 256 + threadIdx.x;
  int c = x & 31, b = x >> 5;
  float p[4], a[4] = {0.f, 0.f, 0.f, 0.f};
  #pragma unroll
  for (int k = 0; k < 4; ++k) p[k] = sigm(dlog[k]);
  size_t ub = ((size_t)(b*Tt + c*LCH)) * Dd + d;
  for (int i = 0; i < LCH; ++i){
    float uv = u[ub];
    U_bf[ub] = f2bf(uv);
    #pragma unroll
    for (int k = 0; k < 4; ++k) a[k] = p[k] * a[k] + uv;
    ub += Dd;
  }
  #pragma unroll
  for (int k = 0; k < 4; ++k)
    vpart[(((size_t)x) * Kk + k) * Dd + d] = a[k];
}

__global__ __launch_bounds__(256) void k_vcomb(const float* __restrict__ vpart,
                                               const float* __restrict__ dlog,
                                               float* __restrict__ vfull){
  int idx = blockIdx.x * 256 + threadIdx.x;
  int k = (idx >> 10) & 3, b = idx >> 12, d = idx & 1023;
  float p  = sigm(dlog[k]);
  float dL = powf(p, (float)LCH);
  float v = 0.f;
  for (int c = 0; c < NCH; ++c)
    v = dL * v + vpart[(((size_t)(b*NCH + c)) * Kk + k) * Dd + d];
  vfull[idx] = v;
}

__global__ __launch_bounds__(256) void k_slast(const float* __restrict__ W_in,
                                               const float* __restrict__ vfull,
                                               const float* __restrict__ s0,
                                               const float* __restrict__ b_in,
                                               const float* __restrict__ dlog,
                                               float* __restrict__ out){
  int gid  = blockIdx.x * 4 + (threadIdx.x >> 6);
  int lane = threadIdx.x & 63;
  int d = gid & 1023, k = (gid >> 10) & 3, b = gid >> 12;
  const float* wrow = W_in + (size_t)(k*Dd + d) * Dd;
  const float* vv   = vfull + ((size_t)(b*Kk + k) << 10);
  float s = 0.f;
  #pragma unroll
  for (int j = 0; j < 16; ++j) s += wrow[lane + j*64] * vv[lane + j*64];
  for (int off = 32; off; off >>= 1) s += __shfl_down(s, off);
  if (lane == 0){
    float p  = sigm(dlog[k]);
    float pT = powf(p, (float)Tt);
    float omp = 1.0f - p;
    float geo = (omp < 1e-12f) ? (float)Tt : (1.0f - pT) / omp;
    out[gid] = pT * s0[gid] + s + b_in[k*Dd + d] * geo;
  }
}

// ---------------------------------------------------------------------------
extern "C" void kernel_launch(void* const* d_in, const int* in_sizes, int n_in,
                              void* d_out, int out_size, void* d_ws, size_t ws_size,
                              hipStream_t stream){
  const float* u     = (const float*)d_in[0];
  const float* s0    = (const float*)d_in[1];
  const float* W_in  = (const float*)d_in[2];
  const float* b_in  = (const float*)d_in[3];
  const float* W_out = (const float*)d_in[4];
  const float* b_out = (const float*)d_in[5];
  const float* dlog  = (const float*)d_in[6];

  float* g_out     = (float*)d_out;                      // B*T*D
  float* slast_out = g_out + (size_t)BT * Dd;            // B*K*D

  char* ws = (char*)d_ws;
  if (ws_size < 115490816ull) return;
  ushort* U_bf    = (ushort*)(ws);                       // 16 MB
  ushort* WinT    = (ushort*)(ws + 16777216);            //  8 MB
  ushort* Wout_bf = (ushort*)(ws + 25165824);            //  8 MB
  ushort* Mcat    = (ushort*)(ws + 33554432);            //  8 MB
  ushort* Y       = (ushort*)(ws + 41943040);            // 64 MB
  float*  carry   = (float*)(ws + 109051904);            //  2 MB
  float*  incoming= (float*)(ws + 111149056);            //  2 MB
  float*  z0buf   = (float*)(ws + 113246208);            // 64 KB
  float*  cterm   = (float*)(ws + 113311744);            // 16 KB
  float*  vpart   = (float*)(ws + 113328128);            //  2 MB
  float*  vfull   = (float*)(ws + 115425280);            // 64 KB

  // prep passes (u, W_out fused, W_in)
  k_prep<<<dim3(128, 4), 256, 0, stream>>>(u, dlog, vpart, U_bf);
  k_wout<<<1024, 256, 0, stream>>>(W_out, s0, b_in, Wout_bf, z0buf, cterm);
  k_transpose<<<dim3(32, 128), dim3(32, 8), 0, stream>>>(W_in, WinT);

  // Mcat[(k,d), d'] = sum_j Wout[d, kD+j] * WinT[d', kD+j]
  gemm_nt<<<dim3(8, 8, 4), 256, 0, stream>>>(Wout_bf, WinT, Mcat,
                                             1024, Ee, Ee, Dd,
                                             1024L, 1024L, 1048576L);
  // Y = U @ Mcat^T: 128^2 tile, 4 blk/CU, conflict-free XOR, fused carries
  gemm_big<<<2048, 256, 0, stream>>>(U_bf, Mcat, Y, dlog, carry);

  // cross-chunk scan + apply
  k_scanInc<<<64, 256, 0, stream>>>(carry, z0buf, dlog, incoming);
  k_scanB<<<dim3(128, 4), 256, 0, stream>>>(Y, incoming, dlog, b_out, cterm, g_out);

  // s_last path
  k_vcomb<<<64, 256, 0, stream>>>(vpart, dlog, vfull);
  k_slast<<<4096, 256, 0, stream>>>(W_in, vfull, s0, b_in, dlog, slast_out);
}

// Round 12
// 154.962 us; speedup vs baseline: 1.2212x; 1.0798x over previous
//
#include <hip/hip_runtime.h>

// ---------------------------------------------------------------------------
// StateBank: g = W_out @ scan(W_in @ u):
//   M_k = W_out_k @ W_in_k; Y = U @ Mcat^T (8192x4096x1024 bf16 GEMM);
//   chunked scan -> g; s_last via weighted time-reduction.
// R12: gemm_big frozen at R11 (87.5us, conflict-free, 4 blk/CU — the
// m97-structure plateau; 6 schedule variants all ~33% MfmaUtil).
// This round: launch fusion 8->5 kernels (k_prep_all / k_mid / k_final)
// + float4/uint vectorization of all aux passes.
// ---------------------------------------------------------------------------

#define Bb 4
#define Tt 2048
#define Dd 1024
#define Kk 4
#define BT (Bb*Tt)          // 8192
#define Ee (Kk*Dd)          // 4096
#define NCH 32              // scan chunks
#define LCH 64              // chunk length (NCH*LCH = T)

typedef __bf16 bf16x8 __attribute__((ext_vector_type(8)));
typedef float  f32x4  __attribute__((ext_vector_type(4)));

__device__ __forceinline__ float bf2f(ushort u){
  union { unsigned int i; float f; } x; x.i = ((unsigned int)u) << 16; return x.f;
}
__device__ __forceinline__ ushort f2bf(float f){
  union { unsigned int i; float f; } x; x.f = f;
  unsigned int i = x.i;
  return (ushort)((i + 0x7FFFu + ((i >> 16) & 1u)) >> 16);   // RNE
}
__device__ __forceinline__ float lo16(unsigned u){
  union { unsigned i; float f; } x; x.i = u << 16; return x.f;
}
__device__ __forceinline__ float hi16(unsigned u){
  union { unsigned i; float f; } x; x.i = u & 0xFFFF0000u; return x.f;
}
__device__ __forceinline__ float sigm(float x){ return 1.0f / (1.0f + expf(-x)); }

// ---------------- fused prep: u-pass | W_in transpose | W_out pass ----------
// grid 1D x 256 threads:
//   [0,128)        : u -> U_bf + vpart (4 d per thread, float4)
//   [128,4224)     : W_in (4096x1024 f32) -> WinT (1024x4096 bf16)
//   [4224,5248)    : W_out -> Wout_bf + z0 + cterm (wave per (k,d) row)
__global__ __launch_bounds__(256) void k_prep_all(
    const float* __restrict__ u, const float* __restrict__ dlog,
    float* __restrict__ vpart, ushort* __restrict__ U_bf,
    const float* __restrict__ W_in, ushort* __restrict__ WinT,
    const float* __restrict__ Wout, const float* __restrict__ s0,
    const float* __restrict__ b_in, ushort* __restrict__ Wout_bf,
    float* __restrict__ z0, float* __restrict__ cterm){
  const int bid = blockIdx.x;
  const int tid = threadIdx.x;

  if (bid < 128){
    // ---- u pass: x = b*NCH + c; thread covers d0..d0+3
    int x = bid, c = x & 31, b = x >> 5;
    int d0 = tid * 4;
    float p[4];
    #pragma unroll
    for (int k = 0; k < 4; ++k) p[k] = sigm(dlog[k]);
    f32x4 a0 = {0,0,0,0}, a1 = {0,0,0,0}, a2 = {0,0,0,0}, a3 = {0,0,0,0};
    size_t ub = ((size_t)(b*Tt + c*LCH)) * Dd + d0;
    for (int i = 0; i < LCH; ++i){
      f32x4 uv = *(const f32x4*)(u + ub);
      ushort4 ob; ob.x = f2bf(uv[0]); ob.y = f2bf(uv[1]);
      ob.z = f2bf(uv[2]); ob.w = f2bf(uv[3]);
      *(ushort4*)(U_bf + ub) = ob;
      a0 = p[0]*a0 + uv; a1 = p[1]*a1 + uv; a2 = p[2]*a2 + uv; a3 = p[3]*a3 + uv;
      ub += Dd;
    }
    size_t vb = ((size_t)x * Kk) * Dd + d0;
    *(f32x4*)(vpart + vb)          = a0;
    *(f32x4*)(vpart + vb + Dd)     = a1;
    *(f32x4*)(vpart + vb + 2*Dd)   = a2;
    *(f32x4*)(vpart + vb + 3*Dd)   = a3;
  } else if (bid < 4224){
    // ---- W_in transpose
    __shared__ float tile[32][33];
    int bb = bid - 128;
    int c0 = (bb & 31) * 32, r0 = (bb >> 5) * 32;
    int tx = tid & 31, ty = tid >> 5;     // 32 x 8
    #pragma unroll
    for (int j = 0; j < 4; ++j)
      tile[ty + j*8][tx] = W_in[(size_t)(r0 + ty + j*8) * Dd + c0 + tx];
    __syncthreads();
    #pragma unroll
    for (int j = 0; j < 4; ++j)
      WinT[(size_t)(c0 + ty + j*8) * Ee + r0 + tx] = f2bf(tile[tx][ty + j*8]);
  } else {
    // ---- W_out pass: wave per gid = k*1024 + d
    int gid  = (bid - 4224) * 4 + (tid >> 6);
    int lane = tid & 63;
    int d = gid & 1023, k = gid >> 10;
    const float* wrow = Wout + (size_t)d * Ee + k * Dd;
    ushort*      wbf  = Wout_bf + (size_t)d * Ee + k * Dd;
    const float* bv   = b_in + k * Dd;
    float sc = 0.f, sz0 = 0.f, sz1 = 0.f, sz2 = 0.f, sz3 = 0.f;
    #pragma unroll
    for (int j = 0; j < 4; ++j){
      int base = lane*4 + j*256;
      float4 wv = *(const float4*)(wrow + base);
      ushort4 ob; ob.x = f2bf(wv.x); ob.y = f2bf(wv.y); ob.z = f2bf(wv.z); ob.w = f2bf(wv.w);
      *(ushort4*)(wbf + base) = ob;
      float4 bb4 = *(const float4*)(bv + base);
      sc += wv.x*bb4.x + wv.y*bb4.y + wv.z*bb4.z + wv.w*bb4.w;
      #pragma unroll
      for (int b = 0; b < 4; ++b){
        const float* sv = s0 + ((size_t)(b*Kk + k) << 10) + base;
        float4 s4 = *(const float4*)sv;
        float acc = wv.x*s4.x + wv.y*s4.y + wv.z*s4.z + wv.w*s4.w;
        if (b == 0) sz0 += acc; else if (b == 1) sz1 += acc;
        else if (b == 2) sz2 += acc; else sz3 += acc;
      }
    }
    for (int off = 32; off; off >>= 1){
      sc  += __shfl_down(sc, off);
      sz0 += __shfl_down(sz0, off);
      sz1 += __shfl_down(sz1, off);
      sz2 += __shfl_down(sz2, off);
      sz3 += __shfl_down(sz3, off);
    }
    if (lane == 0){
      cterm[gid] = sc;
      z0[gid]          = sz0;
      z0[gid + 4096]   = sz1;
      z0[gid + 8192]   = sz2;
      z0[gid + 12288]  = sz3;
    }
  }
}

// ---------------- small NT GEMM (m97 structure) for Mcat --------------------
__global__ __launch_bounds__(256) void gemm_nt(const ushort* __restrict__ A,
                                               const ushort* __restrict__ B,
                                               ushort* __restrict__ C,
                                               int Kred, int lda, int ldb, int ldc,
                                               long aBatch, long bBatch, long cBatch){
  __shared__ ushort As[128 * 32];
  __shared__ ushort Bs[128 * 32];
  A += (long)blockIdx.z * aBatch;
  B += (long)blockIdx.z * bBatch;
  C += (long)blockIdx.z * cBatch;
  const int tid  = threadIdx.x;
  const int lane = tid & 63;
  const int w    = tid >> 6;
  const int wr   = w >> 1, wc = w & 1;
  const int rowBase = blockIdx.x * 128;
  const int colBase = blockIdx.y * 128;

  f32x4 acc[4][4] = {};
  const int krow = (lane >> 4) * 8;
  const int rsel = lane & 15;

  for (int kk = 0; kk < Kred; kk += 32){
    __syncthreads();
    #pragma unroll
    for (int i = 0; i < 2; ++i){
      int c  = i * 256 + tid;
      int r  = c >> 2;
      int c8 = (c & 3) * 8;
      const ushort* ga = A + (size_t)(rowBase + r) * lda + kk + c8;
      const ushort* gb = B + (size_t)(colBase + r) * ldb + kk + c8;
      __builtin_amdgcn_global_load_lds((const __attribute__((address_space(1))) void*)ga,
                                       (__attribute__((address_space(3))) void*)&As[c * 8],
                                       16, 0, 0);
      __builtin_amdgcn_global_load_lds((const __attribute__((address_space(1))) void*)gb,
                                       (__attribute__((address_space(3))) void*)&Bs[c * 8],
                                       16, 0, 0);
    }
    asm volatile("s_waitcnt vmcnt(0)" ::: "memory");
    __syncthreads();

    bf16x8 Af[4], Bf[4];
    #pragma unroll
    for (int mi = 0; mi < 4; ++mi)
      Af[mi] = *(const bf16x8*)&As[(wr*64 + mi*16 + rsel) * 32 + krow];
    #pragma unroll
    for (int ni = 0; ni < 4; ++ni)
      Bf[ni] = *(const bf16x8*)&Bs[(wc*64 + ni*16 + rsel) * 32 + krow];
    #pragma unroll
    for (int mi = 0; mi < 4; ++mi)
      #pragma unroll
      for (int ni = 0; ni < 4; ++ni)
        acc[mi][ni] = __builtin_amdgcn_mfma_f32_16x16x32_bf16(Af[mi], Bf[ni], acc[mi][ni], 0, 0, 0);
  }

  #pragma unroll
  for (int mi = 0; mi < 4; ++mi){
    #pragma unroll
    for (int ni = 0; ni < 4; ++ni){
      int r0 = rowBase + wr*64 + mi*16 + (lane >> 4) * 4;
      int c0 = colBase + wc*64 + ni*16 + (lane & 15);
      #pragma unroll
      for (int q = 0; q < 4; ++q)
        C[(size_t)(r0 + q) * ldc + c0] = f2bf(acc[mi][ni][q]);
    }
  }
}

// ---------------- big GEMM (R11-frozen): 128^2, 4 waves, BK=32, 4 blk/CU ----
#define STAGE_OP(GB, LOFF)                                                     \
  { _Pragma("unroll")                                                          \
    for (int i_ = 0; i_ < 2; ++i_){                                            \
      int c_ = tid + i_*256;                                                   \
      int row_ = c_ >> 2;                                                      \
      int ss_ = (c_ & 3) ^ ((row_ >> 1) & 3);                                  \
      const ushort* g_ = (GB) + (size_t)row_ * 1024 + ss_ * 8;                 \
      __builtin_amdgcn_global_load_lds(                                        \
        (const __attribute__((address_space(1))) void*)g_,                     \
        (__attribute__((address_space(3))) void*)&lds[(LOFF) + c_*8],          \
        16, 0, 0);                                                             \
    } }

#define LOAD_A4(DST)                                                           \
  { _Pragma("unroll")                                                          \
    for (int mi_ = 0; mi_ < 4; ++mi_){                                         \
      int r_ = wm*64 + mi_*16 + rsel;                                          \
      int uo_ = r_*32 + kq*8;                                                  \
      uo_ ^= ((uo_ >> 6) & 3) << 3;                                            \
      DST[mi_] = *(const bf16x8*)&lds[cbase + uo_];                            \
    } }

#define LOAD_B4(DST)                                                           \
  { _Pragma("unroll")                                                          \
    for (int ni_ = 0; ni_ < 4; ++ni_){                                         \
      int r_ = wn*64 + ni_*16 + rsel;                                          \
      int uo_ = r_*32 + kq*8;                                                  \
      uo_ ^= ((uo_ >> 6) & 3) << 3;                                            \
      DST[ni_] = *(const bf16x8*)&lds[cbase + 4096 + uo_];                     \
    } }

#define XB(R) ((((R) & 3) ^ (((R) >> 2) & 3)) << 5)
#define BAR() __builtin_amdgcn_s_barrier()

__global__ __launch_bounds__(256, 4) void gemm_big(const ushort* __restrict__ A,
                                                   const ushort* __restrict__ B,
                                                   ushort* __restrict__ C,
                                                   const float* __restrict__ dlog,
                                                   float* __restrict__ carry){
  __shared__ ushort lds[16384];       // 32 KB -> 4 blocks/CU
  const int tid  = threadIdx.x;
  const int lane = tid & 63;
  const int w    = tid >> 6;          // 0..3
  const int wm   = w >> 1;
  const int wn   = w & 1;
  const int rsel = lane & 15;
  const int kq   = lane >> 4;

  int bid = blockIdx.x;
  int xcd = bid & 7, rr = bid >> 3;
  const int rowBase = ((xcd >> 1) * 16 + (rr & 15)) * 128;
  const int colBase = ((xcd & 1) * 16 + (rr >> 4)) * 128;

  const ushort* Ag = A + (size_t)rowBase * 1024;
  const ushort* Bg = B + (size_t)colBase * 1024;

  f32x4 acc[4][4] = {};

  STAGE_OP(Ag +  0, 0);
  STAGE_OP(Bg +  0, 4096);
  STAGE_OP(Ag + 32, 8192);
  STAGE_OP(Bg + 32, 8192 + 4096);
  asm volatile("s_waitcnt vmcnt(4)" ::: "memory");
  BAR();

  for (int t = 0; t < 32; ++t){
    const int cbase = (t & 1) * 8192;
    bf16x8 af[4], bf[4];
    LOAD_A4(af); LOAD_B4(bf);
    #pragma unroll
    for (int mi = 0; mi < 4; ++mi)
      #pragma unroll
      for (int ni = 0; ni < 4; ++ni)
        acc[mi][ni] = __builtin_amdgcn_mfma_f32_16x16x32_bf16(af[mi], bf[ni], acc[mi][ni], 0, 0, 0);
    asm volatile("s_waitcnt lgkmcnt(0)" ::: "memory");
    BAR();
    if (t < 30){
      STAGE_OP(Ag + (t+2)*32, cbase);
      STAGE_OP(Bg + (t+2)*32, cbase + 4096);
      asm volatile("s_waitcnt vmcnt(4)" ::: "memory");
    } else {
      asm volatile("s_waitcnt vmcnt(0)" ::: "memory");
    }
    BAR();
  }

  // epilogue: C tile -> LDS (XB row-XOR), fused carries, coalesced stores
  #pragma unroll
  for (int mi = 0; mi < 4; ++mi){
    #pragma unroll
    for (int j = 0; j < 4; ++j){
      #pragma unroll
      for (int q = 0; q < 4; ++q){
        int row = wm*64 + mi*16 + (lane >> 4)*4 + q;
        int col = wn*64 + j*16 + rsel;
        int byte = (row*256 + col*2) ^ XB(row);
        *(ushort*)((char*)lds + byte) = f2bf(acc[mi][j][q]);
      }
    }
  }
  __syncthreads();

  if (tid < 128){
    const int k_blk = colBase >> 10;
    const int b_blk = rowBase >> 11;
    const int ch0   = (rowBase & 2047) >> 6;
    const int d0    = colBase & 1023;
    const float p   = sigm(dlog[k_blk]);
    int cp = tid & 63, ch = tid >> 6;
    float a0 = 0.f, a1 = 0.f;
    for (int i = 0; i < 64; ++i){
      int row = ch*64 + i;
      int byte = (row*256 + cp*4) ^ XB(row);
      unsigned v = *(const unsigned*)((char*)lds + byte);
      a0 = p * a0 + lo16(v);
      a1 = p * a1 + hi16(v);
    }
    float* cdst = &carry[(size_t)((b_blk*Kk + k_blk)*NCH + ch0 + ch) * Dd + d0 + cp*2];
    cdst[0] = a0; cdst[1] = a1;
  }

  #pragma unroll
  for (int j = 0; j < 8; ++j){
    int idx = tid + j*256;
    int r = idx >> 4, c16 = idx & 15;
    int byte = (r*256 + c16*16) ^ XB(r);
    f32x4 v = *(const f32x4*)((char*)lds + byte);
    *(f32x4*)&C[(size_t)(rowBase + r) * Ee + colBase + c16*8] = v;
  }
}

// ---------------- fused mid: scanInc | vcomb --------------------------------
__global__ __launch_bounds__(256) void k_mid(const float* __restrict__ carry,
                                             const float* __restrict__ z0,
                                             const float* __restrict__ dlog,
                                             float* __restrict__ incoming,
                                             const float* __restrict__ vpart,
                                             float* __restrict__ vfull){
  int bid = blockIdx.x, tid = threadIdx.x;
  if (bid < 64){
    int idx = bid * 256 + tid;
    int k = (idx >> 10) & 3;
    int bk = idx >> 10, d = idx & 1023;
    float p  = sigm(dlog[k]);
    float dL = powf(p, (float)LCH);
    float inc = z0[idx];
    for (int c = 0; c < NCH; ++c){
      size_t o = ((size_t)(bk * NCH + c)) * Dd + d;
      incoming[o] = inc;
      inc = dL * inc + carry[o];
    }
  } else {
    int idx = (bid - 64) * 256 + tid;
    int k = (idx >> 10) & 3, b = idx >> 12, d = idx & 1023;
    float p  = sigm(dlog[k]);
    float dL = powf(p, (float)LCH);
    float v = 0.f;
    for (int c = 0; c < NCH; ++c)
      v = dL * v + vpart[(((size_t)(b*NCH + c)) * Kk + k) * Dd + d];
    vfull[idx] = v;
  }
}

// ---------------- fused final: scanB (2 d/thread) | slast -------------------
__global__ __launch_bounds__(256) void k_final(const ushort* __restrict__ Y,
                                               const float* __restrict__ incoming,
                                               const float* __restrict__ dlog,
                                               const float* __restrict__ b_out,
                                               const float* __restrict__ cterm,
                                               float* __restrict__ g,
                                               const float* __restrict__ W_in,
                                               const float* __restrict__ vfull,
                                               const float* __restrict__ s0,
                                               const float* __restrict__ b_in,
                                               float* __restrict__ slast){
  int bid = blockIdx.x, tid = threadIdx.x;
  if (bid < 256){
    // scanB: x = bid>>1 (b*NCH+c), d pair = (bid&1)*512 + tid*2
    int x = bid >> 1;
    int c = x & 31, b = x >> 5;
    int d = (bid & 1) * 512 + tid * 2;
    float p[4], ct0[4], ct1[4], pw[4];
    float z0v[4], z1v[4];
    #pragma unroll
    for (int k = 0; k < 4; ++k){
      p[k]  = sigm(dlog[k]);
      size_t io = ((size_t)(((b*Kk + k))*NCH + c)) * Dd + d;
      z0v[k] = incoming[io];
      z1v[k] = incoming[io + 1];
      float omp = fmaxf(1.0f - p[k], 1e-30f);
      ct0[k] = cterm[k * Dd + d] / omp;
      ct1[k] = cterm[k * Dd + d + 1] / omp;
      pw[k] = powf(p[k], (float)(c * LCH + 1));
    }
    float bo0 = b_out[d], bo1 = b_out[d + 1];
    size_t ybase = ((size_t)(b*Tt + c*LCH)) * Ee + d;
    size_t gbase = ((size_t)(b*Tt + c*LCH)) * Dd + d;
    for (int i = 0; i < LCH; ++i){
      float acc0 = bo0, acc1 = bo1;
      #pragma unroll
      for (int k = 0; k < 4; ++k){
        unsigned yv = *(const unsigned*)&Y[ybase + (size_t)k * Dd];
        z0v[k] = p[k] * z0v[k] + lo16(yv);
        z1v[k] = p[k] * z1v[k] + hi16(yv);
        float omw = 1.0f - pw[k];
        acc0 += z0v[k] + ct0[k] * omw;
        acc1 += z1v[k] + ct1[k] * omw;
        pw[k] *= p[k];
      }
      *(float2*)&g[gbase] = make_float2(acc0, acc1);
      ybase += Ee; gbase += Dd;
    }
  } else {
    // slast: wave per gid = (b*K+k)*D + d
    int gid  = (bid - 256) * 4 + (tid >> 6);
    int lane = tid & 63;
    int d = gid & 1023, k = (gid >> 10) & 3, b = gid >> 12;
    const float* wrow = W_in + (size_t)(k*Dd + d) * Dd;
    const float* vv   = vfull + ((size_t)(b*Kk + k) << 10);
    float s = 0.f;
    #pragma unroll
    for (int j = 0; j < 4; ++j){
      int base = lane*4 + j*256;
      float4 w4 = *(const float4*)(wrow + base);
      float4 v4 = *(const float4*)(vv + base);
      s += w4.x*v4.x + w4.y*v4.y + w4.z*v4.z + w4.w*v4.w;
    }
    for (int off = 32; off; off >>= 1) s += __shfl_down(s, off);
    if (lane == 0){
      float p  = sigm(dlog[k]);
      float pT = powf(p, (float)Tt);
      float omp = 1.0f - p;
      float geo = (omp < 1e-12f) ? (float)Tt : (1.0f - pT) / omp;
      slast[gid] = pT * s0[gid] + s + b_in[k*Dd + d] * geo;
    }
  }
}

// ---------------------------------------------------------------------------
extern "C" void kernel_launch(void* const* d_in, const int* in_sizes, int n_in,
                              void* d_out, int out_size, void* d_ws, size_t ws_size,
                              hipStream_t stream){
  const float* u     = (const float*)d_in[0];
  const float* s0    = (const float*)d_in[1];
  const float* W_in  = (const float*)d_in[2];
  const float* b_in  = (const float*)d_in[3];
  const float* W_out = (const float*)d_in[4];
  const float* b_out = (const float*)d_in[5];
  const float* dlog  = (const float*)d_in[6];

  float* g_out     = (float*)d_out;                      // B*T*D
  float* slast_out = g_out + (size_t)BT * Dd;            // B*K*D

  char* ws = (char*)d_ws;
  if (ws_size < 115490816ull) return;
  ushort* U_bf    = (ushort*)(ws);                       // 16 MB
  ushort* WinT    = (ushort*)(ws + 16777216);            //  8 MB
  ushort* Wout_bf = (ushort*)(ws + 25165824);            //  8 MB
  ushort* Mcat    = (ushort*)(ws + 33554432);            //  8 MB
  ushort* Y       = (ushort*)(ws + 41943040);            // 64 MB
  float*  carry   = (float*)(ws + 109051904);            //  2 MB
  float*  incoming= (float*)(ws + 111149056);            //  2 MB
  float*  z0buf   = (float*)(ws + 113246208);            // 64 KB
  float*  cterm   = (float*)(ws + 113311744);            // 16 KB
  float*  vpart   = (float*)(ws + 113328128);            //  2 MB
  float*  vfull   = (float*)(ws + 115425280);            // 64 KB

  // 1) fused prep: u-pass [0,128) | W_in transpose [128,4224) | W_out [4224,5248)
  k_prep_all<<<5248, 256, 0, stream>>>(u, dlog, vpart, U_bf,
                                       W_in, WinT,
                                       W_out, s0, b_in, Wout_bf, z0buf, cterm);

  // 2) Mcat[(k,d), d'] = sum_j Wout[d, kD+j] * WinT[d', kD+j]
  gemm_nt<<<dim3(8, 8, 4), 256, 0, stream>>>(Wout_bf, WinT, Mcat,
                                             1024, Ee, Ee, Dd,
                                             1024L, 1024L, 1048576L);
  // 3) Y = U @ Mcat^T + fused chunk carries
  gemm_big<<<2048, 256, 0, stream>>>(U_bf, Mcat, Y, dlog, carry);

  // 4) fused mid: scanInc [0,64) | vcomb [64,128)
  k_mid<<<128, 256, 0, stream>>>(carry, z0buf, dlog, incoming, vpart, vfull);

  // 5) fused final: scanB [0,256) | slast [256,4352)
  k_final<<<4352, 256, 0, stream>>>(Y, incoming, dlog, b_out, cterm, g_out,
                                    W_in, vfull, s0, b_in, slast_out);
}